// Round 3
// baseline (305.498 us; speedup 1.0000x reference)
//
#include <hip/hip_runtime.h>

// FMFMNeuron: snntorch Leaky neuron scan, T=50, B=500k.
//   cur[t,b]  = s[t,b,0]*w1 + s[t,b,1]*w2
//   reset     = (mem_{t-1} > 1);  mem = 0.95*mem + cur - reset;  spk = (mem > 1)
// Memory-bound streaming: 200 MB in + 100 MB out => ~48 us at 6.3 TB/s.
//
// R2/R3: explicit prefetch ring (PF=10) over the fully-unrolled T loop.
// R1's unroll-5 had a batch pipeline (5 loads -> wait -> 5 computes/stores ->
// next 5 loads): ~900 cyc HBM latency exposed per body, ~60% BW at 4 waves/SIMD.
// The ring keeps 10 float4 loads (10 KB/wave) permanently in flight.
// R3 fix: __builtin_nontemporal_store needs a native clang vector type, not
// HIP's float2 class -> use ext_vector_type(2).
//
// Numerics: outputs are hard thresholds of mem; match numpy's op-by-op fp32
// rounding exactly (no FMA contraction) via __fmul_rn/__fadd_rn/__fsub_rn.
// (mem-1>0) == (mem>1) exactly in fp32 (Sterbenz), so direct compare is safe.

constexpr int T_STEPS = 50;
constexpr int BATCH   = 500000;
constexpr int HALF    = BATCH / 2;   // 2 neurons per thread
constexpr int PF      = 10;          // prefetch distance (float4 loads in flight)

typedef float v2f __attribute__((ext_vector_type(2)));

__global__ __launch_bounds__(256)
void snn_leaky_kernel(const float4* __restrict__ in4,   // [T][HALF] float4 = 2 neurons' (s0,s1)
                      const float*  __restrict__ W,     // [2]
                      v2f*          __restrict__ out2)  // [T][HALF]
{
    const int i = blockIdx.x * blockDim.x + threadIdx.x;
    if (i >= HALF) return;

    const float w1 = W[0];
    const float w2 = W[1];

    float mem0 = 0.0f, mem1 = 0.0f;

    const float4* __restrict__ p = in4 + i;
    v2f*          __restrict__ q = out2 + i;

    // Prime the ring: PF independent loads in flight before any compute.
    float4 buf[PF];
    #pragma unroll
    for (int k = 0; k < PF; ++k)
        buf[k] = p[(size_t)k * HALF];

    // Full unroll: ring indices become static, buf[] stays in VGPRs, and the
    // compiler can emit fine-grained s_waitcnt vmcnt(N) per consumed slot.
    #pragma unroll
    for (int t = 0; t < T_STEPS; ++t) {
        const float4 s = buf[t % PF];
        if (t + PF < T_STEPS)
            buf[t % PF] = p[(size_t)(t + PF) * HALF];  // refill ring immediately

        // cur = (s0*w1) + (s1*w2), separately rounded (matches numpy einsum)
        const float cur0 = __fadd_rn(__fmul_rn(s.x, w1), __fmul_rn(s.y, w2));
        const float cur1 = __fadd_rn(__fmul_rn(s.z, w1), __fmul_rn(s.w, w2));

        // reset from PREVIOUS mem
        const float r0 = (mem0 > 1.0f) ? 1.0f : 0.0f;
        const float r1 = (mem1 > 1.0f) ? 1.0f : 0.0f;

        // mem = ((0.95*mem) + cur) - reset, separately rounded
        mem0 = __fsub_rn(__fadd_rn(__fmul_rn(0.95f, mem0), cur0), r0);
        mem1 = __fsub_rn(__fadd_rn(__fmul_rn(0.95f, mem1), cur1), r1);

        v2f spk;
        spk.x = (mem0 > 1.0f) ? 1.0f : 0.0f;
        spk.y = (mem1 > 1.0f) ? 1.0f : 0.0f;
        // Nontemporal: output is streamed once, never re-read by this kernel.
        __builtin_nontemporal_store(spk, &q[(size_t)t * HALF]);
    }
}

extern "C" void kernel_launch(void* const* d_in, const int* in_sizes, int n_in,
                              void* d_out, int out_size, void* d_ws, size_t ws_size,
                              hipStream_t stream) {
    const float4* in4 = (const float4*)d_in[0];   // spike_seq [T,B,2] fp32
    const float*  W   = (const float*)d_in[1];    // [1,2] fp32
    v2f*          out = (v2f*)d_out;              // spk_rec [T,B,1] fp32

    const int threads = 256;
    const int blocks  = (HALF + threads - 1) / threads;  // 977
    snn_leaky_kernel<<<blocks, threads, 0, stream>>>(in4, W, out);
}

// Round 4
// 289.725 us; speedup vs baseline: 1.0544x; 1.0544x over previous
//
#include <hip/hip_runtime.h>

// FMFMNeuron: snntorch Leaky neuron scan, T=50, B=500k.
//   cur[t,b]  = s[t,b,0]*w1 + s[t,b,1]*w2
//   reset     = (mem_{t-1} > 1);  mem = 0.95*mem + cur - reset;  spk = (mem > 1)
// Memory-bound streaming: 200 MB in + 100 MB out => ~48 us floor at 6.3 TB/s.
//
// R4: 4 neurons/thread. Per step: 2x float4 nt loads + 1x float4 nt store
// (16 B/lane store sweet spot). Halves store instruction count / vmcnt queue
// pressure vs R3's float2 stores; tests whether vmcnt in-order retirement
// (stores interleaved with ring loads) was the ~65-vs-48us gap.
// Grid: 125k threads = 1.9 waves/SIMD; in-flight bytes/CU ~76 KB >> 9.2 KB
// Little's-law need, VALUBusy ~5%, so low occupancy is safe.
//
// Numerics: outputs are hard thresholds of mem; match numpy's op-by-op fp32
// rounding exactly (no FMA contraction) via __fmul_rn/__fadd_rn/__fsub_rn.
// (mem-1>0) == (mem>1) exactly in fp32 (Sterbenz), so direct compare is safe.

constexpr int T_STEPS = 50;
constexpr int BATCH   = 500000;
constexpr int QUART   = BATCH / 4;   // 4 neurons per thread = 125000 threads
constexpr int PF      = 5;           // ring depth in t-steps (2 loads each)

typedef float v4f __attribute__((ext_vector_type(4)));

__global__ __launch_bounds__(256)
void snn_leaky_kernel(const v4f* __restrict__ in4,   // [T][B/2] float4; thread i owns idx 2i,2i+1
                      const float* __restrict__ W,   // [2]
                      v4f*        __restrict__ out4) // [T][B/4]
{
    const int i = blockIdx.x * blockDim.x + threadIdx.x;
    if (i >= QUART) return;

    const float w1 = W[0];
    const float w2 = W[1];

    float m0 = 0.0f, m1 = 0.0f, m2 = 0.0f, m3 = 0.0f;

    const v4f* __restrict__ p = in4 + (size_t)2 * i;   // 2 float4 per t
    v4f*       __restrict__ q = out4 + i;

    // Prime the ring: PF t-steps (2 independent nt loads each) in flight.
    v4f bufA[PF], bufB[PF];
    #pragma unroll
    for (int k = 0; k < PF; ++k) {
        const v4f* r = p + (size_t)k * (BATCH / 2);
        bufA[k] = __builtin_nontemporal_load(r);
        bufB[k] = __builtin_nontemporal_load(r + 1);
    }

    #pragma unroll
    for (int t = 0; t < T_STEPS; ++t) {
        const v4f sA = bufA[t % PF];   // neurons 4i,4i+1: (s0,s1,s0,s1)
        const v4f sB = bufB[t % PF];   // neurons 4i+2,4i+3
        if (t + PF < T_STEPS) {
            const v4f* r = p + (size_t)(t + PF) * (BATCH / 2);
            bufA[t % PF] = __builtin_nontemporal_load(r);
            bufB[t % PF] = __builtin_nontemporal_load(r + 1);
        }

        // cur = (s0*w1) + (s1*w2), separately rounded (matches numpy einsum)
        const float c0 = __fadd_rn(__fmul_rn(sA.x, w1), __fmul_rn(sA.y, w2));
        const float c1 = __fadd_rn(__fmul_rn(sA.z, w1), __fmul_rn(sA.w, w2));
        const float c2 = __fadd_rn(__fmul_rn(sB.x, w1), __fmul_rn(sB.y, w2));
        const float c3 = __fadd_rn(__fmul_rn(sB.z, w1), __fmul_rn(sB.w, w2));

        // reset from PREVIOUS mem
        const float r0 = (m0 > 1.0f) ? 1.0f : 0.0f;
        const float r1 = (m1 > 1.0f) ? 1.0f : 0.0f;
        const float r2 = (m2 > 1.0f) ? 1.0f : 0.0f;
        const float r3 = (m3 > 1.0f) ? 1.0f : 0.0f;

        // mem = ((0.95*mem) + cur) - reset, separately rounded
        m0 = __fsub_rn(__fadd_rn(__fmul_rn(0.95f, m0), c0), r0);
        m1 = __fsub_rn(__fadd_rn(__fmul_rn(0.95f, m1), c1), r1);
        m2 = __fsub_rn(__fadd_rn(__fmul_rn(0.95f, m2), c2), r2);
        m3 = __fsub_rn(__fadd_rn(__fmul_rn(0.95f, m3), c3), r3);

        v4f spk;
        spk.x = (m0 > 1.0f) ? 1.0f : 0.0f;
        spk.y = (m1 > 1.0f) ? 1.0f : 0.0f;
        spk.z = (m2 > 1.0f) ? 1.0f : 0.0f;
        spk.w = (m3 > 1.0f) ? 1.0f : 0.0f;
        __builtin_nontemporal_store(spk, &q[(size_t)t * QUART]);
    }
}

extern "C" void kernel_launch(void* const* d_in, const int* in_sizes, int n_in,
                              void* d_out, int out_size, void* d_ws, size_t ws_size,
                              hipStream_t stream) {
    const v4f*   in4 = (const v4f*)d_in[0];   // spike_seq [T,B,2] fp32
    const float* W   = (const float*)d_in[1]; // [1,2] fp32
    v4f*         out = (v4f*)d_out;           // spk_rec [T,B,1] fp32

    const int threads = 256;
    const int blocks  = (QUART + threads - 1) / threads;  // 489
    snn_leaky_kernel<<<blocks, threads, 0, stream>>>(in4, W, out);
}